// Round 1
// baseline (1075.457 us; speedup 1.0000x reference)
//
#include <hip/hip_runtime.h>

#define NEG_SLOPE 0.2f

// ---------------- workspace layout (bytes) ----------------
#define WS_HIST1 0                         // 4 * 65536 * 4  = 1 MB
#define WS_HISTA (WS_HIST1 + 4*65536*4)    // 1 MB
#define WS_DBL   (WS_HISTA + 4*65536*4)    // 88 doubles: [0..59] sum_i, [60..71] sum_j, [72..79] sum_x, [80..87] sum_x2
#define WS_SEL   (WS_DBL + 88*8)           // 16 ints: p0[4] r0[4] p1[4] r1[4]
#define WS_MINP1 (WS_SEL + 16*4)           // 4 uints (init 0xFF)
#define WS_RMED  (WS_MINP1 + 4*4)          // 4 floats
#define WS_BLV   (WS_RMED + 4*4)           // 60 floats blv[(b*3+c)*5+t]

__device__ __forceinline__ float leakyf(float x) { return x >= 0.f ? x : NEG_SLOPE * x; }

// ---------------- stats over i: per-plane sums, center-frame stats & median hist pass 1 ----------------
__global__ __launch_bounds__(256) void stats_i_kernel(const float* __restrict__ gi,
                                                      double* __restrict__ sums,
                                                      unsigned int* __restrict__ hist1) {
  const int plane = blockIdx.y;          // (b*3+c)*5+t, 0..59
  const int chunk = blockIdx.x;          // 0..31
  const int b = plane / 15;
  const int rem = plane % 15;
  const int c = rem / 5;
  const int t = rem % 5;
  const int tid = threadIdx.x;
  const float4* base = (const float4*)(gi + (size_t)plane * 262144);
  const bool domed = (c == 0 && t == 2);
  const bool dostat = (c >= 1 && t == 2);
  double dsum = 0.0, dsx = 0.0, dsx2 = 0.0;
  for (int k = 0; k < 8; ++k) {
    float4 v = base[chunk * 2048 + k * 256 + tid];
    dsum += (double)v.x + (double)v.y + (double)v.z + (double)v.w;
    if (domed || dostat) {
      float arr[4] = {v.x, v.y, v.z, v.w};
#pragma unroll
      for (int q = 0; q < 4; ++q) {
        float x = fminf(fmaxf(arr[q], 0.f), 1.f) * 255.f;
        if (domed) {
          unsigned int u = __float_as_uint(x);     // non-negative floats: bits are order-preserving
          atomicAdd(&hist1[b * 65536 + (u >> 16)], 1u);
        } else {
          dsx += (double)x;
          dsx2 += (double)x * (double)x;
        }
      }
    }
  }
  __shared__ double red[256];
  red[tid] = dsum; __syncthreads();
  for (int off = 128; off > 0; off >>= 1) { if (tid < off) red[tid] += red[tid + off]; __syncthreads(); }
  if (tid == 0) atomicAdd(&sums[plane], red[0]);
  __syncthreads();
  if (dostat) {   // uniform per block
    red[tid] = dsx; __syncthreads();
    for (int off = 128; off > 0; off >>= 1) { if (tid < off) red[tid] += red[tid + off]; __syncthreads(); }
    if (tid == 0) atomicAdd(&sums[72 + b * 2 + (c - 1)], red[0]);
    __syncthreads();
    red[tid] = dsx2; __syncthreads();
    for (int off = 128; off > 0; off >>= 1) { if (tid < off) red[tid] += red[tid + off]; __syncthreads(); }
    if (tid == 0) atomicAdd(&sums[80 + b * 2 + (c - 1)], red[0]);
  }
}

// ---------------- stats over j ----------------
__global__ __launch_bounds__(256) void stats_j_kernel(const float* __restrict__ gj,
                                                      double* __restrict__ sums) {
  const int plane = blockIdx.y;          // b*3+c, 0..11
  const int chunk = blockIdx.x;
  const int tid = threadIdx.x;
  const float4* base = (const float4*)(gj + (size_t)plane * 262144);
  double dsum = 0.0;
  for (int k = 0; k < 8; ++k) {
    float4 v = base[chunk * 2048 + k * 256 + tid];
    dsum += (double)v.x + (double)v.y + (double)v.z + (double)v.w;
  }
  __shared__ double red[256];
  red[tid] = dsum; __syncthreads();
  for (int off = 128; off > 0; off >>= 1) { if (tid < off) red[tid] += red[tid + off]; __syncthreads(); }
  if (tid == 0) atomicAdd(&sums[60 + plane], red[0]);
}

// ---------------- median selection pass 1 scan: find 16-bit prefix + rank for k0,k1 ----------------
__global__ __launch_bounds__(256) void scan1_kernel(const unsigned int* __restrict__ hist1,
                                                    int* __restrict__ sel) {
  const int b = blockIdx.x, tid = threadIdx.x;
  const unsigned int* h = hist1 + b * 65536;
  unsigned int tot = 0;
  for (int q = 0; q < 256; ++q) tot += h[tid * 256 + q];
  __shared__ unsigned int s[256];
  s[tid] = tot; __syncthreads();
  for (int off = 1; off < 256; off <<= 1) {
    unsigned int v = (tid >= off) ? s[tid - off] : 0u;
    __syncthreads();
    s[tid] += v;
    __syncthreads();
  }
  unsigned int pref = s[tid] - tot;      // exclusive prefix
  unsigned int ks[2] = {131071u, 131072u};
#pragma unroll
  for (int m = 0; m < 2; ++m) {
    unsigned int k = ks[m];
    if (k >= pref && k < pref + tot) {
      unsigned int cum = pref;
      for (int q = 0; q < 256; ++q) {
        unsigned int cnt = h[tid * 256 + q];
        if (k < cum + cnt) { sel[m * 8 + b] = tid * 256 + q; sel[m * 8 + 4 + b] = (int)(k - cum); break; }
        cum += cnt;
      }
    }
  }
}

// ---------------- median pass 2: low-16-bit histogram within selected prefix ----------------
__global__ __launch_bounds__(256) void hist2_kernel(const float* __restrict__ gi,
                                                    const int* __restrict__ sel,
                                                    unsigned int* __restrict__ histA,
                                                    unsigned int* __restrict__ minp1) {
  const int b = blockIdx.y, chunk = blockIdx.x, tid = threadIdx.x;
  const unsigned int p0 = (unsigned int)sel[b];
  const unsigned int p1 = (unsigned int)sel[8 + b];
  const float4* base = (const float4*)(gi + (size_t)(b * 15 + 2) * 262144);  // center frame, ch 0
  for (int k = 0; k < 8; ++k) {
    float4 v = base[chunk * 2048 + k * 256 + tid];
    float arr[4] = {v.x, v.y, v.z, v.w};
#pragma unroll
    for (int q = 0; q < 4; ++q) {
      float x = fminf(fmaxf(arr[q], 0.f), 1.f) * 255.f;
      unsigned int u = __float_as_uint(x);
      unsigned int up = u >> 16;
      if (up == p0) atomicAdd(&histA[b * 65536 + (u & 0xFFFFu)], 1u);
      if (up == p1) atomicMin(&minp1[b], u);   // min element of bucket p1 (used when p1 != p0 -> r1 == 0)
    }
  }
}

// ---------------- median pass 2 scan: exact order statistics -> r_med ----------------
__global__ __launch_bounds__(256) void scan2_kernel(const unsigned int* __restrict__ histA,
                                                    const int* __restrict__ sel,
                                                    const unsigned int* __restrict__ minp1,
                                                    float* __restrict__ rmed) {
  const int b = blockIdx.x, tid = threadIdx.x;
  const int p0 = sel[b], r0 = sel[4 + b], p1 = sel[8 + b], r1 = sel[12 + b];
  const unsigned int* h = histA + b * 65536;
  unsigned int tot = 0;
  for (int q = 0; q < 256; ++q) tot += h[tid * 256 + q];
  __shared__ unsigned int s[256];
  __shared__ float v0s, v1s;
  s[tid] = tot; __syncthreads();
  for (int off = 1; off < 256; off <<= 1) {
    unsigned int v = (tid >= off) ? s[tid - off] : 0u;
    __syncthreads();
    s[tid] += v;
    __syncthreads();
  }
  unsigned int pref = s[tid] - tot;
  if ((unsigned)r0 >= pref && (unsigned)r0 < pref + tot) {
    unsigned int cum = pref;
    for (int q = 0; q < 256; ++q) {
      unsigned int cnt = h[tid * 256 + q];
      if ((unsigned)r0 < cum + cnt) { v0s = __uint_as_float(((unsigned)p0 << 16) | (unsigned)(tid * 256 + q)); break; }
      cum += cnt;
    }
  }
  if (p1 == p0 && (unsigned)r1 >= pref && (unsigned)r1 < pref + tot) {
    unsigned int cum = pref;
    for (int q = 0; q < 256; ++q) {
      unsigned int cnt = h[tid * 256 + q];
      if ((unsigned)r1 < cum + cnt) { v1s = __uint_as_float(((unsigned)p1 << 16) | (unsigned)(tid * 256 + q)); break; }
      cum += cnt;
    }
  }
  __syncthreads();
  if (tid == 0) {
    float v1 = (p1 == p0) ? v1s : __uint_as_float(minp1[b]);
    rmed[b] = 0.5f * (v0s + v1);
  }
}

// ---------------- finalize: bl2d + MLP -> blv[(b*3+c)*5+t] ----------------
__global__ void finalize_kernel(const double* __restrict__ sums, const float* __restrict__ rmed,
                                const float* __restrict__ w_bl1, const float* __restrict__ b_bl1,
                                const float* __restrict__ w_bl2, const float* __restrict__ b_bl2,
                                const float* __restrict__ w1, float* __restrict__ blv) {
  const int idx = threadIdx.x;
  if (idx >= 20) return;
  const int b = idx / 5, t = idx % 5;
  const double inv = 1.0 / 262144.0;
  float bl2[3];
  bl2[0] = 140.f / (1.f + 14.4f * expf(-0.034f * rmed[b]));
  for (int c = 1; c < 3; ++c) {
    double m = sums[72 + b * 2 + (c - 1)] * inv;
    double ex2 = sums[80 + b * 2 + (c - 1)] * inv;
    double var = ex2 - m * m;
    if (var < 0.0) var = 0.0;
    bl2[c] = (float)(1.13 * m + 1.11 * sqrt(var) - 25.6);
  }
#pragma unroll
  for (int c = 0; c < 3; ++c)
    bl2[c] = fminf(fmaxf(bl2[c], 5.f), 250.f) * (1.f / 255.f);
  float diff[3];
  for (int c = 0; c < 3; ++c)
    diff[c] = (float)((sums[(b * 3 + c) * 5 + t] - sums[60 + b * 3 + c]) * inv);
  float h1[16];
  for (int o = 0; o < 16; ++o) {
    float s = b_bl1[o];
    for (int c = 0; c < 3; ++c) s += w_bl1[o * 3 + c] * diff[c];
    h1[o] = leakyf(s);
  }
  const float w1v = w1[0];
  for (int c = 0; c < 3; ++c) {
    float s = b_bl2[c];
    for (int o = 0; o < 16; ++o) s += w_bl2[c * 16 + o] * h1[o];
    float sg = 1.f / (1.f + expf(-s));
    blv[(b * 3 + c) * 5 + t] = bl2[c] + w1v * sg;
  }
}

// ---------------- fused x -> conv1(3->16)+leaky -> conv2(16->1)+sigmoid, + bl broadcast ----------------
__global__ __launch_bounds__(256) void fused_kernel(
    const float* __restrict__ gi, const float* __restrict__ gj,
    const float* __restrict__ w_t1, const float* __restrict__ b_t1,
    const float* __restrict__ w_t2, const float* __restrict__ b_t2,
    const float* __restrict__ w2p, const float* __restrict__ t_bias,
    const float* __restrict__ blv, float* __restrict__ out) {
  __shared__ float jt[1200];          // j tile [3][20][20]
  __shared__ float xls[3][1200];      // rolling x tiles, slot = frame % 3
  __shared__ float h2s[16 * 324];     // h2 tile [16][18][18]
  __shared__ float blv_s[15];

  const int b = blockIdx.z, tY = blockIdx.y, tX = blockIdx.x;
  const int tid = threadIdx.x;
  const int ty = tid >> 4, tx = tid & 15;
  const int gy = tY * 16 + ty, gx = tX * 16 + tx;
  const int ybase = tY * 16 - 2, xbase = tX * 16 - 2;

  if (tid < 15) blv_s[tid] = blv[b * 15 + tid];

  for (int idx = tid; idx < 1200; idx += 256) {
    int c = idx / 400, rem = idx % 400;
    int ys = rem / 20, xsx = rem % 20;
    int gyy = ybase + ys, gxx = xbase + xsx;
    float v = 0.f;
    if (gyy >= 0 && gyy < 512 && gxx >= 0 && gxx < 512)
      v = gj[((b * 3 + c) * 512 + gyy) * 512 + gxx];
    jt[idx] = v;
  }
  __syncthreads();

  // bl output (pure broadcast of blv)
#pragma unroll
  for (int c = 0; c < 3; ++c)
#pragma unroll
    for (int t = 0; t < 5; ++t)
      out[(((b * 3 + c) * 5 + t) * 512 + gy) * 512 + gx] = blv_s[c * 5 + t];

  const float w2v = w2p[0];
  float acc[5] = {0.f, 0.f, 0.f, 0.f, 0.f};

  for (int tf = 0; tf < 5; ++tf) {
    // stage new x frame(s) into rolling slots (frame f -> slot f%3)
    const int f_lo = (tf == 0) ? 0 : tf + 1;
    for (int f = f_lo; f <= tf + 1 && f < 5; ++f) {
      const int slot = f % 3;
      for (int idx = tid; idx < 1200; idx += 256) {
        int c = idx / 400, rem = idx % 400;
        int ys = rem / 20, xsx = rem % 20;
        int gyy = ybase + ys, gxx = xbase + xsx;
        float xv = 0.f;
        if (gyy >= 0 && gyy < 512 && gxx >= 0 && gxx < 512) {
          float iv = gi[(((b * 3 + c) * 5 + f) * 512 + gyy) * 512 + gxx];
          float bv = blv_s[c * 5 + f];
          float t3 = (iv - bv) / (jt[idx] - bv + 1e-8f);
          xv = iv + w2v * t3;
        }
        xls[slot][idx] = xv;
      }
    }
    __syncthreads();

    // conv1: h2 tile (18x18 halo), 16 channels; window reg-cached, reused by all 16 c_out
    for (int pos = tid; pos < 324; pos += 256) {
      const int y0 = pos / 18, x0 = pos % 18;
      const int gyy = tY * 16 - 1 + y0, gxx = tX * 16 - 1 + x0;
      const bool inimg = (gyy >= 0 && gyy < 512 && gxx >= 0 && gxx < 512);
      float a[16];
#pragma unroll
      for (int o = 0; o < 16; ++o) a[o] = b_t1[o];
      if (inimg) {
#pragma unroll
        for (int kd = 0; kd < 3; ++kd) {
          const int f = tf + kd - 1;
          if (f < 0 || f >= 5) continue;    // uniform
          const int slot = f % 3;
          float xv[27];
#pragma unroll
          for (int ci = 0; ci < 3; ++ci)
#pragma unroll
            for (int kh = 0; kh < 3; ++kh)
#pragma unroll
              for (int kw = 0; kw < 3; ++kw)
                xv[ci * 9 + kh * 3 + kw] = xls[slot][ci * 400 + (y0 + kh) * 20 + (x0 + kw)];
#pragma unroll
          for (int o = 0; o < 16; ++o) {
            float s = 0.f;
#pragma unroll
            for (int q = 0; q < 27; ++q) {
              const int ci = q / 9, r = q % 9;
              s += w_t1[o * 81 + ci * 27 + kd * 9 + r] * xv[q];   // wave-uniform -> scalar loads
            }
            a[o] += s;
          }
        }
      }
#pragma unroll
      for (int o = 0; o < 16; ++o)
        h2s[o * 324 + pos] = inimg ? leakyf(a[o]) : 0.f;
    }
    __syncthreads();

    // conv2: this h2 frame contributes to outputs t = tf-1 (kd=2), tf (kd=1), tf+1 (kd=0)
    float s_m1 = 0.f, s_0 = 0.f, s_p1 = 0.f;
#pragma unroll
    for (int c = 0; c < 16; ++c) {
      float hv[9];
#pragma unroll
      for (int kh = 0; kh < 3; ++kh)
#pragma unroll
        for (int kw = 0; kw < 3; ++kw)
          hv[kh * 3 + kw] = h2s[c * 324 + (ty + kh) * 18 + (tx + kw)];
#pragma unroll
      for (int q = 0; q < 9; ++q) s_p1 += w_t2[c * 27 + q] * hv[q];
#pragma unroll
      for (int q = 0; q < 9; ++q) s_0 += w_t2[c * 27 + 9 + q] * hv[q];
#pragma unroll
      for (int q = 0; q < 9; ++q) s_m1 += w_t2[c * 27 + 18 + q] * hv[q];
    }
    // uniform-branch accumulation keeps acc[] in registers (literal indices only)
    if (tf == 1) acc[0] += s_m1; else if (tf == 2) acc[1] += s_m1;
    else if (tf == 3) acc[2] += s_m1; else if (tf == 4) acc[3] += s_m1;
    if (tf == 0) acc[0] += s_0; else if (tf == 1) acc[1] += s_0;
    else if (tf == 2) acc[2] += s_0; else if (tf == 3) acc[3] += s_0; else acc[4] += s_0;
    if (tf == 0) acc[1] += s_p1; else if (tf == 1) acc[2] += s_p1;
    else if (tf == 2) acc[3] += s_p1; else if (tf == 3) acc[4] += s_p1;
    __syncthreads();
  }

  const float bt2 = b_t2[0];
#pragma unroll
  for (int t = 0; t < 5; ++t) {
    float tv = 1.f / (1.f + __expf(-(acc[t] + bt2))) + t_bias[t];
    out[15728640 + ((b * 5 + t) * 512 + gy) * 512 + gx] = tv;
  }
}

extern "C" void kernel_launch(void* const* d_in, const int* in_sizes, int n_in,
                              void* d_out, int out_size, void* d_ws, size_t ws_size,
                              hipStream_t stream) {
  const float* gi = (const float*)d_in[0];
  const float* gj = (const float*)d_in[1];
  const float* w_bl1 = (const float*)d_in[2];
  const float* b_bl1 = (const float*)d_in[3];
  const float* w_bl2 = (const float*)d_in[4];
  const float* b_bl2 = (const float*)d_in[5];
  const float* w_t1 = (const float*)d_in[6];
  const float* b_t1 = (const float*)d_in[7];
  const float* w_t2 = (const float*)d_in[8];
  const float* b_t2 = (const float*)d_in[9];
  const float* w1 = (const float*)d_in[10];
  const float* w2 = (const float*)d_in[11];
  const float* t_bias = (const float*)d_in[12];
  float* out = (float*)d_out;
  char* ws = (char*)d_ws;

  unsigned int* hist1 = (unsigned int*)(ws + WS_HIST1);
  unsigned int* histA = (unsigned int*)(ws + WS_HISTA);
  double* sums = (double*)(ws + WS_DBL);
  int* sel = (int*)(ws + WS_SEL);
  unsigned int* minp1 = (unsigned int*)(ws + WS_MINP1);
  float* rmed = (float*)(ws + WS_RMED);
  float* blv = (float*)(ws + WS_BLV);

  hipMemsetAsync(ws, 0, WS_MINP1, stream);               // zero hist1, histA, sums, sel
  hipMemsetAsync(ws + WS_MINP1, 0xFF, 16, stream);       // minp1 = UINT_MAX

  stats_i_kernel<<<dim3(32, 60), 256, 0, stream>>>(gi, sums, hist1);
  stats_j_kernel<<<dim3(32, 12), 256, 0, stream>>>(gj, sums);
  scan1_kernel<<<4, 256, 0, stream>>>(hist1, sel);
  hist2_kernel<<<dim3(32, 4), 256, 0, stream>>>(gi, sel, histA, minp1);
  scan2_kernel<<<4, 256, 0, stream>>>(histA, sel, minp1, rmed);
  finalize_kernel<<<1, 32, 0, stream>>>(sums, rmed, w_bl1, b_bl1, w_bl2, b_bl2, w1, blv);
  fused_kernel<<<dim3(32, 32, 4), 256, 0, stream>>>(gi, gj, w_t1, b_t1, w_t2, b_t2, w2, t_bias, blv, out);
}

// Round 3
// 260.279 us; speedup vs baseline: 4.1319x; 4.1319x over previous
//
#include <hip/hip_runtime.h>

typedef unsigned int uint;
typedef unsigned short ushort;
typedef short bf16x8 __attribute__((ext_vector_type(8)));
typedef float f32x4 __attribute__((ext_vector_type(4)));
typedef _Float16 half2v __attribute__((ext_vector_type(2)));

#define NEG_SLOPE 0.2f

// ---------------- workspace layout (bytes) ----------------
#define WS_HIST 0                       // 4*4096*4 = 65536
#define WS_DBL  65536                   // 88 doubles: [0..59] sum_i, [60..71] sum_j, [72..79] sx, [80..87] sx2
#define WS_BLV  (WS_DBL + 704)          // 60 floats
#define WS_WA   (WS_BLV + 256)          // 16*128 bf16 = 4096 B (16-aligned: 66496)
#define WS_W2PK (WS_WA + 4096)          // 216 dwords = 864 B
#define WS_ZERO_BYTES (WS_DBL + 704)    // zero hist + sums

__device__ __forceinline__ float leakyf(float x) { return fmaxf(x, NEG_SLOPE * x); }

__device__ __forceinline__ ushort f2bf(float f) {
  uint u = __float_as_uint(f);
  uint r = u + 0x7FFFu + ((u >> 16) & 1u);
  return (ushort)(r >> 16);
}
__device__ __forceinline__ half2v as_h2(uint u) { union { uint x; half2v h; } c; c.x = u; return c.h; }
__device__ __forceinline__ uint h2u(half2v h) { union { uint x; half2v h; } c; c.h = h; return c.x; }

// ---------------- per-plane sums over i + center-frame G/B stats ----------------
__global__ __launch_bounds__(256) void stats_i_kernel(const float* __restrict__ gi,
                                                      double* __restrict__ sums) {
  const int plane = blockIdx.y;          // (b*3+c)*5+t
  const int chunk = blockIdx.x;          // 0..31
  const int b = plane / 15;
  const int rem = plane % 15;
  const int c = rem / 5;
  const int t = rem % 5;
  const int tid = threadIdx.x;
  const float4* base = (const float4*)(gi + (size_t)plane * 262144);
  const bool dostat = (c >= 1 && t == 2);
  double dsum = 0.0, dsx = 0.0, dsx2 = 0.0;
  for (int k = 0; k < 8; ++k) {
    float4 v = base[chunk * 2048 + k * 256 + tid];
    dsum += (double)v.x + (double)v.y + (double)v.z + (double)v.w;
    if (dostat) {
      float arr[4] = {v.x, v.y, v.z, v.w};
#pragma unroll
      for (int q = 0; q < 4; ++q) {
        float x = fminf(fmaxf(arr[q], 0.f), 1.f) * 255.f;
        dsx += (double)x;
        dsx2 += (double)x * (double)x;
      }
    }
  }
  __shared__ double red[256];
  red[tid] = dsum; __syncthreads();
  for (int off = 128; off > 0; off >>= 1) { if (tid < off) red[tid] += red[tid + off]; __syncthreads(); }
  if (tid == 0) atomicAdd(&sums[plane], red[0]);
  __syncthreads();
  if (dostat) {
    red[tid] = dsx; __syncthreads();
    for (int off = 128; off > 0; off >>= 1) { if (tid < off) red[tid] += red[tid + off]; __syncthreads(); }
    if (tid == 0) atomicAdd(&sums[72 + b * 2 + (c - 1)], red[0]);
    __syncthreads();
    red[tid] = dsx2; __syncthreads();
    for (int off = 128; off > 0; off >>= 1) { if (tid < off) red[tid] += red[tid + off]; __syncthreads(); }
    if (tid == 0) atomicAdd(&sums[80 + b * 2 + (c - 1)], red[0]);
  }
}

// ---------------- sums over j ----------------
__global__ __launch_bounds__(256) void stats_j_kernel(const float* __restrict__ gj,
                                                      double* __restrict__ sums) {
  const int plane = blockIdx.y;          // b*3+c
  const int chunk = blockIdx.x;
  const int tid = threadIdx.x;
  const float4* base = (const float4*)(gj + (size_t)plane * 262144);
  double dsum = 0.0;
  for (int k = 0; k < 8; ++k) {
    float4 v = base[chunk * 2048 + k * 256 + tid];
    dsum += (double)v.x + (double)v.y + (double)v.z + (double)v.w;
  }
  __shared__ double red[256];
  red[tid] = dsum; __syncthreads();
  for (int off = 128; off > 0; off >>= 1) { if (tid < off) red[tid] += red[tid + off]; __syncthreads(); }
  if (tid == 0) atomicAdd(&sums[60 + plane], red[0]);
}

// ---------------- binned median histogram (LDS-privatized); err <= 0.031/255-scale ----------------
__global__ __launch_bounds__(256) void median_hist_kernel(const float* __restrict__ gi,
                                                          uint* __restrict__ hist) {
  __shared__ uint lh[4096];
  const int b = blockIdx.y, chunk = blockIdx.x, tid = threadIdx.x;
  for (int i = tid; i < 4096; i += 256) lh[i] = 0;
  __syncthreads();
  const float4* base = (const float4*)(gi + (size_t)(b * 15 + 2) * 262144);  // center frame, R
  for (int k = 0; k < 8; ++k) {
    float4 v = base[chunk * 2048 + k * 256 + tid];
    float a[4] = {v.x, v.y, v.z, v.w};
#pragma unroll
    for (int q = 0; q < 4; ++q) {
      float x = fminf(fmaxf(a[q], 0.f), 1.f) * 255.f;
      int bin = (int)(x * (4096.0f / 255.0f));
      if (bin > 4095) bin = 4095;
      atomicAdd(&lh[bin], 1u);
    }
  }
  __syncthreads();
  for (int i = tid; i < 4096; i += 256) { uint v = lh[i]; if (v) atomicAdd(&hist[b * 4096 + i], v); }
}

// ---------------- weight prep: padded bf16 A-matrix (16x128) + packed half2 conv2 weights ----------------
__global__ void setup_kernel(const float* __restrict__ w_t1, const float* __restrict__ w_t2,
                             ushort* __restrict__ wA, uint* __restrict__ w2pk) {
  const int tid = threadIdx.x;
  for (int idx = tid; idx < 2048; idx += 256) {
    int o = idx >> 7, k = idx & 127, g = k >> 2, kw = k & 3;
    float v = 0.f;
    if (g < 27 && kw < 3) {
      int ci = g / 9, kd = (g % 9) / 3, kh = g % 3;
      v = w_t1[o * 81 + ci * 27 + kd * 9 + kh * 3 + kw];
    }
    wA[idx] = f2bf(v);
  }
  for (int idx = tid; idx < 216; idx += 256) {
    int cp = idx & 7, r = (idx >> 3) % 3, tp = idx / 24;
    int kh = tp / 3, kw = tp % 3;
    float w0 = w_t2[(2 * cp) * 27 + r * 9 + kh * 3 + kw];
    float w1 = w_t2[(2 * cp + 1) * 27 + r * 9 + kh * 3 + kw];
    half2v hh; hh[0] = (_Float16)w0; hh[1] = (_Float16)w1;
    w2pk[idx] = h2u(hh);
  }
}

// ---------------- finalize: median scan + stats -> MLP -> blv ----------------
__global__ __launch_bounds__(256) void finalize_kernel(const uint* __restrict__ hist,
                                const double* __restrict__ sums,
                                const float* __restrict__ w_bl1, const float* __restrict__ b_bl1,
                                const float* __restrict__ w_bl2, const float* __restrict__ b_bl2,
                                const float* __restrict__ w1, float* __restrict__ blv) {
  __shared__ uint s[256];
  __shared__ float fv[2];
  __shared__ float rmed_s[4];
  const int tid = threadIdx.x;
  for (int b = 0; b < 4; ++b) {
    const uint* h = hist + b * 4096;
    uint loc[16]; uint part = 0;
#pragma unroll
    for (int q = 0; q < 16; ++q) { loc[q] = h[tid * 16 + q]; part += loc[q]; }
    s[tid] = part; __syncthreads();
    for (int off = 1; off < 256; off <<= 1) {
      uint v = (tid >= off) ? s[tid - off] : 0u;
      __syncthreads(); s[tid] += v; __syncthreads();
    }
    uint pref = s[tid] - part;
#pragma unroll
    for (int m = 0; m < 2; ++m) {
      uint k = 131071u + (uint)m;
      if (k >= pref && k < pref + part) {
        uint cum = pref;
        for (int q = 0; q < 16; ++q) {
          if (k < cum + loc[q]) { fv[m] = ((float)(tid * 16 + q) + 0.5f) * (255.f / 4096.f); break; }
          cum += loc[q];
        }
      }
    }
    __syncthreads();
    if (tid == 0) rmed_s[b] = 0.5f * (fv[0] + fv[1]);
    __syncthreads();
  }
  if (tid < 20) {
    const int b = tid / 5, t = tid % 5;
    const double inv = 1.0 / 262144.0;
    float bl2[3];
    bl2[0] = 140.f / (1.f + 14.4f * expf(-0.034f * rmed_s[b]));
    for (int c = 1; c < 3; ++c) {
      double m = sums[72 + b * 2 + (c - 1)] * inv;
      double ex2 = sums[80 + b * 2 + (c - 1)] * inv;
      double var = ex2 - m * m;
      if (var < 0.0) var = 0.0;
      bl2[c] = (float)(1.13 * m + 1.11 * sqrt(var) - 25.6);
    }
#pragma unroll
    for (int c = 0; c < 3; ++c)
      bl2[c] = fminf(fmaxf(bl2[c], 5.f), 250.f) * (1.f / 255.f);
    float diff[3];
    for (int c = 0; c < 3; ++c)
      diff[c] = (float)((sums[(b * 3 + c) * 5 + t] - sums[60 + b * 3 + c]) * inv);
    float h1[16];
    for (int o = 0; o < 16; ++o) {
      float sv = b_bl1[o];
      for (int c = 0; c < 3; ++c) sv += w_bl1[o * 3 + c] * diff[c];
      h1[o] = leakyf(sv);
    }
    const float w1v = w1[0];
    for (int c = 0; c < 3; ++c) {
      float sv = b_bl2[c];
      for (int o = 0; o < 16; ++o) sv += w_bl2[c * 16 + o] * h1[o];
      float sg = 1.f / (1.f + expf(-sv));
      blv[(b * 3 + c) * 5 + t] = bl2[c] + w1v * sg;
    }
  }
}

// ---------------- fused: x -> conv1 (MFMA bf16) -> leaky -> conv2 (fdot2 f16) -> sigmoid ----------------
// x-tile LDS: bf16, 2 copies x 4 slots(3 rolling + 1 zero) x 3ci x 20y x 22x
// copy stride 5280 elems, slot 1320, ci 440, row 22.
// copy1 linear index m (addr 5280+m) holds x[m+1]: write xsh[eb+5279]=x[eb] (xx>0);
// read col x0 (odd) at addr linear(x0-1)+5280  (even -> 4B-aligned).
// h2 LDS: f16 [18y][18x][24ch-stride] (48B x-stride, 16 used).
__global__ __launch_bounds__(256) void fused_kernel(
    const float* __restrict__ gi, const float* __restrict__ gj,
    const ushort* __restrict__ wAg, const float* __restrict__ b_t1,
    const uint* __restrict__ w2pk, const float* __restrict__ b_t2,
    const float* __restrict__ w2p, const float* __restrict__ t_bias,
    const float* __restrict__ blv, float* __restrict__ out) {
  __shared__ __align__(16) ushort xsh[10560];
  __shared__ __align__(16) ushort h2sh[18 * 18 * 24];
  __shared__ float blv_s[15];

  const int b = blockIdx.z, tY = blockIdx.y, tX = blockIdx.x;
  const int tid = threadIdx.x;
  const int wv = tid >> 6;               // wave id 0..3
  const int lane = tid & 63;
  const int ln = lane & 15;              // MFMA row/col lane
  const int kb = lane >> 4;              // k-block 0..3
  const int ty = tid >> 4, tx = tid & 15;
  const int gy = tY * 16 + ty, gx = tX * 16 + tx;
  const int ybase = tY * 16 - 2, xbase = tX * 16 - 2;

  if (tid < 15) blv_s[tid] = blv[b * 15 + tid];
  // zero whole x region (covers parity pads + zero-slot; avoids NaN*0 in MFMA pads)
  for (int i = tid; i < 5280; i += 256) ((uint*)xsh)[i] = 0u;

  // A fragments + bias (per lane)
  union { uint4 u; bf16x8 v; } a4[4];
#pragma unroll
  for (int m = 0; m < 4; ++m)
    a4[m].u = *(const uint4*)(wAg + ln * 128 + m * 32 + kb * 8);
  f32x4 bias4;
#pragma unroll
  for (int r = 0; r < 4; ++r) bias4[r] = b_t1[kb * 4 + r];

  // static per-lane group descriptors: e = m*2+j -> g = m*8 + kb*2 + j
  int sbase[8], kdE[8];
#pragma unroll
  for (int e = 0; e < 8; ++e) {
    int m = e >> 1, j = e & 1;
    int g = m * 8 + kb * 2 + j;
    int ci = 0, kd = 0, kh = 0;
    if (g < 27) { ci = g / 9; kd = (g % 9) / 3; kh = g % 3; } else { kd = 99; }  // kd=99 -> zero slot
    sbase[e] = ci * 440 + kh * 22;
    kdE[e] = kd;
  }

  __syncthreads();

  // bl output (broadcast)
#pragma unroll
  for (int c = 0; c < 3; ++c)
#pragma unroll
    for (int t = 0; t < 5; ++t)
      out[(((b * 3 + c) * 5 + t) * 512 + gy) * 512 + gx] = blv_s[c * 5 + t];

  const float w2v = w2p[0];
  float acc5[5] = {0.f, 0.f, 0.f, 0.f, 0.f};

#pragma unroll 1
  for (int tf = 0; tf < 5; ++tf) {
    // ---- stage x frame(s): frame f -> slot f%3 (bf16, 2 parity copies) ----
    const int f_lo = (tf == 0) ? 0 : tf + 1;
    for (int f = f_lo; f <= tf + 1 && f < 5; ++f) {
      const int slot = f % 3;
      for (int idx = tid; idx < 1200; idx += 256) {
        int ci = idx / 400, rem = idx % 400;
        int ys = rem / 20, xx = rem % 20;
        int gyy = ybase + ys, gxx = xbase + xx;
        float xv = 0.f;
        if (gyy >= 0 && gyy < 512 && gxx >= 0 && gxx < 512) {
          float iv = gi[(((b * 3 + ci) * 5 + f) * 512 + gyy) * 512 + gxx];
          float jv = gj[((b * 3 + ci) * 512 + gyy) * 512 + gxx];
          float bv = blv_s[ci * 5 + f];
          xv = iv + w2v * ((iv - bv) / (jv - bv + 1e-8f));
        }
        ushort hx = f2bf(xv);
        int eb = slot * 1320 + ci * 440 + ys * 22 + xx;
        xsh[eb] = hx;
        if (xx > 0) xsh[eb + 5279] = hx;   // copy1[eb-1] = x[eb]
      }
    }
    __syncthreads();

    // ---- per-tf slot bases ----
    int baseE[8];
#pragma unroll
    for (int e = 0; e < 8; ++e) {
      int f = tf + kdE[e] - 1;
      int sl = (f < 0 || f > 4 || kdE[e] == 99) ? 3 : (f % 3);
      baseE[e] = sbase[e] + sl * 1320;
    }

    // ---- conv1 via MFMA: 21 pos-tiles of 16 over 18x18 h2 grid ----
    for (int tile = wv; tile < 21; tile += 4) {
      int pos = tile * 16 + ln;
      int pe = pos < 324 ? pos : 323;
      int y0 = pe / 18;
      int x0 = pe - y0 * 18;
      int p = x0 & 1;
      int q = y0 * 22 + x0 - p + p * 5280;   // FIXED: was p*5279 (off-by-one col shift + misaligned dword)
      uint u0[8], u1[8];
#pragma unroll
      for (int e = 0; e < 8; ++e) {
        const uint* pu = (const uint*)(xsh + (baseE[e] + q));
        u0[e] = pu[0]; u1[e] = pu[1];
      }
      f32x4 acc = bias4;
#pragma unroll
      for (int m = 0; m < 4; ++m) {
        union { uint4 u; bf16x8 v; } bfr;
        bfr.u = make_uint4(u0[2 * m], u1[2 * m], u0[2 * m + 1], u1[2 * m + 1]);
        acc = __builtin_amdgcn_mfma_f32_16x16x32_bf16(a4[m].v, bfr.v, acc, 0, 0, 0);
      }
      int gyh = tY * 16 - 1 + y0, gxh = tX * 16 - 1 + x0;
      bool inimg = (gyh >= 0) && (gyh < 512) && (gxh >= 0) && (gxh < 512);
      float r0 = inimg ? leakyf(acc[0]) : 0.f;
      float r1 = inimg ? leakyf(acc[1]) : 0.f;
      float r2 = inimg ? leakyf(acc[2]) : 0.f;
      float r3 = inimg ? leakyf(acc[3]) : 0.f;
      half2v p0, p1;
      p0[0] = (_Float16)r0; p0[1] = (_Float16)r1;
      p1[0] = (_Float16)r2; p1[1] = (_Float16)r3;
      if (pos < 324)
        *(uint2*)(h2sh + (y0 * 18 + x0) * 24 + kb * 4) = make_uint2(h2u(p0), h2u(p1));
    }
    __syncthreads();

    // ---- conv2 via fdot2: 16 channels interleaved, 27 taps, 3 kd-slices ----
    float s0 = 0.f, s1 = 0.f, s2 = 0.f;
#pragma unroll
    for (int kh = 0; kh < 3; ++kh) {
#pragma unroll
      for (int kw = 0; kw < 3; ++kw) {
        const ushort* hp = h2sh + ((ty + kh) * 18 + tx + kw) * 24;
        uint4 ha = *(const uint4*)hp;
        uint4 hb = *(const uint4*)(hp + 8);
        uint hd[8] = {ha.x, ha.y, ha.z, ha.w, hb.x, hb.y, hb.z, hb.w};
        const uint* wr0 = w2pk + ((kh * 3 + kw) * 3 + 0) * 8;
        const uint* wr1 = wr0 + 8;
        const uint* wr2 = wr0 + 16;
#pragma unroll
        for (int cp = 0; cp < 8; ++cp) {
          s0 = __builtin_amdgcn_fdot2(as_h2(hd[cp]), as_h2(wr0[cp]), s0, false);
          s1 = __builtin_amdgcn_fdot2(as_h2(hd[cp]), as_h2(wr1[cp]), s1, false);
          s2 = __builtin_amdgcn_fdot2(as_h2(hd[cp]), as_h2(wr2[cp]), s2, false);
        }
      }
    }
    // r=0 (kd=0) -> t=tf+1 ; r=1 -> t=tf ; r=2 -> t=tf-1
    if (tf == 1) acc5[0] += s2; else if (tf == 2) acc5[1] += s2;
    else if (tf == 3) acc5[2] += s2; else if (tf == 4) acc5[3] += s2;
    if (tf == 0) acc5[0] += s1; else if (tf == 1) acc5[1] += s1;
    else if (tf == 2) acc5[2] += s1; else if (tf == 3) acc5[3] += s1; else acc5[4] += s1;
    if (tf == 0) acc5[1] += s0; else if (tf == 1) acc5[2] += s0;
    else if (tf == 2) acc5[3] += s0; else if (tf == 3) acc5[4] += s0;
    __syncthreads();
  }

  const float bt2 = b_t2[0];
#pragma unroll
  for (int t = 0; t < 5; ++t) {
    float tv = 1.f / (1.f + __expf(-(acc5[t] + bt2))) + t_bias[t];
    out[15728640 + ((b * 5 + t) * 512 + gy) * 512 + gx] = tv;
  }
}

extern "C" void kernel_launch(void* const* d_in, const int* in_sizes, int n_in,
                              void* d_out, int out_size, void* d_ws, size_t ws_size,
                              hipStream_t stream) {
  const float* gi = (const float*)d_in[0];
  const float* gj = (const float*)d_in[1];
  const float* w_bl1 = (const float*)d_in[2];
  const float* b_bl1 = (const float*)d_in[3];
  const float* w_bl2 = (const float*)d_in[4];
  const float* b_bl2 = (const float*)d_in[5];
  const float* w_t1 = (const float*)d_in[6];
  const float* b_t1 = (const float*)d_in[7];
  const float* w_t2 = (const float*)d_in[8];
  const float* b_t2 = (const float*)d_in[9];
  const float* w1 = (const float*)d_in[10];
  const float* w2 = (const float*)d_in[11];
  const float* t_bias = (const float*)d_in[12];
  float* out = (float*)d_out;
  char* ws = (char*)d_ws;

  uint* hist = (uint*)(ws + WS_HIST);
  double* sums = (double*)(ws + WS_DBL);
  float* blv = (float*)(ws + WS_BLV);
  ushort* wA = (ushort*)(ws + WS_WA);
  uint* w2pk = (uint*)(ws + WS_W2PK);

  hipMemsetAsync(ws, 0, WS_ZERO_BYTES, stream);

  setup_kernel<<<1, 256, 0, stream>>>(w_t1, w_t2, wA, w2pk);
  stats_i_kernel<<<dim3(32, 60), 256, 0, stream>>>(gi, sums);
  stats_j_kernel<<<dim3(32, 12), 256, 0, stream>>>(gj, sums);
  median_hist_kernel<<<dim3(32, 4), 256, 0, stream>>>(gi, hist);
  finalize_kernel<<<1, 256, 0, stream>>>(hist, sums, w_bl1, b_bl1, w_bl2, b_bl2, w1, blv);
  fused_kernel<<<dim3(32, 32, 4), 256, 0, stream>>>(gi, gj, wA, b_t1, w2pk, b_t2, w2, t_bias, blv, out);
}

// Round 4
// 217.613 us; speedup vs baseline: 4.9421x; 1.1961x over previous
//
#include <hip/hip_runtime.h>

typedef unsigned int uint;
typedef unsigned short ushort;
typedef short bf16x8 __attribute__((ext_vector_type(8)));
typedef _Float16 f16x8 __attribute__((ext_vector_type(8)));
typedef float f32x4 __attribute__((ext_vector_type(4)));
typedef _Float16 half2v __attribute__((ext_vector_type(2)));

#define NEG_SLOPE 0.2f

// ---------------- workspace layout (bytes) ----------------
#define WS_HIST 0                       // 4*4096*4 = 65536
#define WS_DBL  65536                   // 88 doubles
#define WS_BLV  (WS_DBL + 704)         // 60 floats
#define WS_WA   (WS_BLV + 256)        // 16x128 bf16 = 4096 B (66496, 16-aligned)
#define WS_W2A  (WS_WA + 4096)        // 5tf x 5step x 64lane x 8 f16 = 25600 B (70592, 16-aligned)
#define WS_ZERO_BYTES (WS_DBL + 704)

__device__ __forceinline__ float leakyf(float x) { return fmaxf(x, NEG_SLOPE * x); }

__device__ __forceinline__ ushort f2bf(float f) {
  uint u = __float_as_uint(f);
  uint r = u + 0x7FFFu + ((u >> 16) & 1u);
  return (ushort)(r >> 16);
}
__device__ __forceinline__ uint h2u(half2v h) { union { uint x; half2v h; } c; c.h = h; return c.x; }

// ---------------- per-plane sums over i + center-frame G/B stats ----------------
__global__ __launch_bounds__(256) void stats_i_kernel(const float* __restrict__ gi,
                                                      double* __restrict__ sums) {
  const int plane = blockIdx.y;
  const int chunk = blockIdx.x;
  const int b = plane / 15;
  const int rem = plane % 15;
  const int c = rem / 5;
  const int t = rem % 5;
  const int tid = threadIdx.x;
  const float4* base = (const float4*)(gi + (size_t)plane * 262144);
  const bool dostat = (c >= 1 && t == 2);
  double dsum = 0.0, dsx = 0.0, dsx2 = 0.0;
  for (int k = 0; k < 8; ++k) {
    float4 v = base[chunk * 2048 + k * 256 + tid];
    dsum += (double)v.x + (double)v.y + (double)v.z + (double)v.w;
    if (dostat) {
      float arr[4] = {v.x, v.y, v.z, v.w};
#pragma unroll
      for (int q = 0; q < 4; ++q) {
        float x = fminf(fmaxf(arr[q], 0.f), 1.f) * 255.f;
        dsx += (double)x;
        dsx2 += (double)x * (double)x;
      }
    }
  }
  __shared__ double red[256];
  red[tid] = dsum; __syncthreads();
  for (int off = 128; off > 0; off >>= 1) { if (tid < off) red[tid] += red[tid + off]; __syncthreads(); }
  if (tid == 0) atomicAdd(&sums[plane], red[0]);
  __syncthreads();
  if (dostat) {
    red[tid] = dsx; __syncthreads();
    for (int off = 128; off > 0; off >>= 1) { if (tid < off) red[tid] += red[tid + off]; __syncthreads(); }
    if (tid == 0) atomicAdd(&sums[72 + b * 2 + (c - 1)], red[0]);
    __syncthreads();
    red[tid] = dsx2; __syncthreads();
    for (int off = 128; off > 0; off >>= 1) { if (tid < off) red[tid] += red[tid + off]; __syncthreads(); }
    if (tid == 0) atomicAdd(&sums[80 + b * 2 + (c - 1)], red[0]);
  }
}

// ---------------- sums over j ----------------
__global__ __launch_bounds__(256) void stats_j_kernel(const float* __restrict__ gj,
                                                      double* __restrict__ sums) {
  const int plane = blockIdx.y;
  const int chunk = blockIdx.x;
  const int tid = threadIdx.x;
  const float4* base = (const float4*)(gj + (size_t)plane * 262144);
  double dsum = 0.0;
  for (int k = 0; k < 8; ++k) {
    float4 v = base[chunk * 2048 + k * 256 + tid];
    dsum += (double)v.x + (double)v.y + (double)v.z + (double)v.w;
  }
  __shared__ double red[256];
  red[tid] = dsum; __syncthreads();
  for (int off = 128; off > 0; off >>= 1) { if (tid < off) red[tid] += red[tid + off]; __syncthreads(); }
  if (tid == 0) atomicAdd(&sums[60 + plane], red[0]);
}

// ---------------- binned median histogram (LDS-privatized) ----------------
__global__ __launch_bounds__(256) void median_hist_kernel(const float* __restrict__ gi,
                                                          uint* __restrict__ hist) {
  __shared__ uint lh[4096];
  const int b = blockIdx.y, chunk = blockIdx.x, tid = threadIdx.x;
  for (int i = tid; i < 4096; i += 256) lh[i] = 0;
  __syncthreads();
  const float4* base = (const float4*)(gi + (size_t)(b * 15 + 2) * 262144);
  for (int k = 0; k < 8; ++k) {
    float4 v = base[chunk * 2048 + k * 256 + tid];
    float a[4] = {v.x, v.y, v.z, v.w};
#pragma unroll
    for (int q = 0; q < 4; ++q) {
      float x = fminf(fmaxf(a[q], 0.f), 1.f) * 255.f;
      int bin = (int)(x * (4096.0f / 255.0f));
      if (bin > 4095) bin = 4095;
      atomicAdd(&lh[bin], 1u);
    }
  }
  __syncthreads();
  for (int i = tid; i < 4096; i += 256) { uint v = lh[i]; if (v) atomicAdd(&hist[b * 4096 + i], v); }
}

// ---------------- weight prep: bf16 conv1 A (16x128) + f16 conv2 A-table ----------------
// w2A[(tf*5+step)*64 + lane][j]: A row = lane&15 = output t, k = (lane>>4)*8+j,
// tap = step*2 + (k>>4), ch = k&15; value = w_t2[ch, kd=tf+1-t, tap] (0 outside).
__global__ void setup_kernel(const float* __restrict__ w_t1, const float* __restrict__ w_t2,
                             ushort* __restrict__ wA, ushort* __restrict__ w2A) {
  const int tid = threadIdx.x;
  for (int idx = tid; idx < 2048; idx += 256) {
    int o = idx >> 7, k = idx & 127, g = k >> 2, kw = k & 3;
    float v = 0.f;
    if (g < 27 && kw < 3) {
      int ci = g / 9, kd = (g % 9) / 3, kh = g % 3;
      v = w_t1[o * 81 + ci * 27 + kd * 9 + kh * 3 + kw];
    }
    wA[idx] = f2bf(v);
  }
  for (int idx = tid; idx < 12800; idx += 256) {
    int j = idx & 7;
    int lane = (idx >> 3) & 63;
    int rest = idx >> 9;            // 0..24
    int step = rest % 5;
    int tf = rest / 5;
    int ln = lane & 15, kb = lane >> 4;
    int k = kb * 8 + j;
    int tap = step * 2 + (k >> 4);
    int ch = k & 15;
    float v = 0.f;
    if (ln < 5 && tap < 9) {
      int kd = tf + 1 - ln;
      if (kd >= 0 && kd <= 2) v = w_t2[ch * 27 + kd * 9 + tap];
    }
    union { ushort s; _Float16 h; } cv; cv.h = (_Float16)v;
    w2A[idx] = cv.s;
  }
}

// ---------------- finalize: median scan + stats -> MLP -> blv ----------------
__global__ __launch_bounds__(256) void finalize_kernel(const uint* __restrict__ hist,
                                const double* __restrict__ sums,
                                const float* __restrict__ w_bl1, const float* __restrict__ b_bl1,
                                const float* __restrict__ w_bl2, const float* __restrict__ b_bl2,
                                const float* __restrict__ w1, float* __restrict__ blv) {
  __shared__ uint s[256];
  __shared__ float fv[2];
  __shared__ float rmed_s[4];
  const int tid = threadIdx.x;
  for (int b = 0; b < 4; ++b) {
    const uint* h = hist + b * 4096;
    uint loc[16]; uint part = 0;
#pragma unroll
    for (int q = 0; q < 16; ++q) { loc[q] = h[tid * 16 + q]; part += loc[q]; }
    s[tid] = part; __syncthreads();
    for (int off = 1; off < 256; off <<= 1) {
      uint v = (tid >= off) ? s[tid - off] : 0u;
      __syncthreads(); s[tid] += v; __syncthreads();
    }
    uint pref = s[tid] - part;
#pragma unroll
    for (int m = 0; m < 2; ++m) {
      uint k = 131071u + (uint)m;
      if (k >= pref && k < pref + part) {
        uint cum = pref;
        for (int q = 0; q < 16; ++q) {
          if (k < cum + loc[q]) { fv[m] = ((float)(tid * 16 + q) + 0.5f) * (255.f / 4096.f); break; }
          cum += loc[q];
        }
      }
    }
    __syncthreads();
    if (tid == 0) rmed_s[b] = 0.5f * (fv[0] + fv[1]);
    __syncthreads();
  }
  if (tid < 20) {
    const int b = tid / 5, t = tid % 5;
    const double inv = 1.0 / 262144.0;
    float bl2[3];
    bl2[0] = 140.f / (1.f + 14.4f * expf(-0.034f * rmed_s[b]));
    for (int c = 1; c < 3; ++c) {
      double m = sums[72 + b * 2 + (c - 1)] * inv;
      double ex2 = sums[80 + b * 2 + (c - 1)] * inv;
      double var = ex2 - m * m;
      if (var < 0.0) var = 0.0;
      bl2[c] = (float)(1.13 * m + 1.11 * sqrt(var) - 25.6);
    }
#pragma unroll
    for (int c = 0; c < 3; ++c)
      bl2[c] = fminf(fmaxf(bl2[c], 5.f), 250.f) * (1.f / 255.f);
    float diff[3];
    for (int c = 0; c < 3; ++c)
      diff[c] = (float)((sums[(b * 3 + c) * 5 + t] - sums[60 + b * 3 + c]) * inv);
    float h1[16];
    for (int o = 0; o < 16; ++o) {
      float sv = b_bl1[o];
      for (int c = 0; c < 3; ++c) sv += w_bl1[o * 3 + c] * diff[c];
      h1[o] = leakyf(sv);
    }
    const float w1v = w1[0];
    for (int c = 0; c < 3; ++c) {
      float sv = b_bl2[c];
      for (int o = 0; o < 16; ++o) sv += w_bl2[c * 16 + o] * h1[o];
      float sg = 1.f / (1.f + expf(-sv));
      blv[(b * 3 + c) * 5 + t] = bl2[c] + w1v * sg;
    }
  }
}

// ---------------- fused: x -> conv1 (MFMA bf16) -> leaky -> conv2 (MFMA f16) -> sigmoid ----------------
__global__ __launch_bounds__(256) void fused_kernel(
    const float* __restrict__ gi, const float* __restrict__ gj,
    const ushort* __restrict__ wAg, const float* __restrict__ b_t1,
    const ushort* __restrict__ w2Ag, const float* __restrict__ b_t2,
    const float* __restrict__ w2p, const float* __restrict__ t_bias,
    const float* __restrict__ blv, float* __restrict__ out) {
  __shared__ __align__(16) ushort xsh[10560];     // x tiles: 2 parity copies x 4 slots x [3][20][22] bf16
  __shared__ __align__(16) ushort h2sh[18 * 18 * 24];  // h2 f16 [18y][18x][24ch-stride]
  __shared__ float blv_s[15];

  const int b = blockIdx.z, tY = blockIdx.y, tX = blockIdx.x;
  const int tid = threadIdx.x;
  const int wv = tid >> 6;
  const int lane = tid & 63;
  const int ln = lane & 15;
  const int kb = lane >> 4;
  const int ty = tid >> 4, tx = tid & 15;
  const int gy = tY * 16 + ty, gx = tX * 16 + tx;
  const int ybase = tY * 16 - 2, xbase = tX * 16 - 2;

  if (tid < 15) blv_s[tid] = blv[b * 15 + tid];
  for (int i = tid; i < 5280; i += 256) ((uint*)xsh)[i] = 0u;

  // conv1 A fragments + bias
  union { uint4 u; bf16x8 v; } a4[4];
#pragma unroll
  for (int m = 0; m < 4; ++m)
    a4[m].u = *(const uint4*)(wAg + ln * 128 + m * 32 + kb * 8);
  f32x4 bias4;
#pragma unroll
  for (int r = 0; r < 4; ++r) bias4[r] = b_t1[kb * 4 + r];

  // conv1 per-lane k-group descriptors
  int sbase[8], kdE[8];
#pragma unroll
  for (int e = 0; e < 8; ++e) {
    int m = e >> 1, j = e & 1;
    int g = m * 8 + kb * 2 + j;
    int ci = 0, kd = 0, kh = 0;
    if (g < 27) { ci = g / 9; kd = (g % 9) / 3; kh = g % 3; } else { kd = 99; }
    sbase[e] = ci * 440 + kh * 22;
    kdE[e] = kd;
  }

  // conv2 per-lane B offsets (elem units): tap paired 2/step along K=32
  int bOff[5];
#pragma unroll
  for (int s = 0; s < 5; ++s) {
    int tap = s * 2 + (kb >> 1); if (tap > 8) tap = 8;   // pad tap: A is zero there
    int kh = tap / 3, kw = tap - kh * 3;
    bOff[s] = kh * 432 + kw * 24 + (kb & 1) * 8 + ln * 24;
  }

  // staging precompute (k = 0..4, idx = tid + k*256 over [3][20][20])
  int qi5[5], eb5[5], civ5[5];
  float jv5[5];
  uint vmask = 0;
#pragma unroll
  for (int k = 0; k < 5; ++k) {
    int idx = tid + k * 256;
    int idc = idx < 1200 ? idx : 0;
    int ci = idc / 400, rem = idc - ci * 400;
    int ys = rem / 20, xx = rem - ys * 20;
    int gyy = ybase + ys, gxx = xbase + xx;
    bool inb = (idx < 1200) && gyy >= 0 && gyy < 512 && gxx >= 0 && gxx < 512;
    int cy = gyy < 0 ? 0 : (gyy > 511 ? 511 : gyy);
    int cx = gxx < 0 ? 0 : (gxx > 511 ? 511 : gxx);
    int spc = cy * 512 + cx;
    qi5[k] = (b * 3 + ci) * 1310720 + spc;
    jv5[k] = gj[(b * 3 + ci) * 262144 + spc];
    eb5[k] = ci * 440 + ys * 22 + xx;
    civ5[k] = ci * 5;
    if (inb) vmask |= 1u << k;
    if (xx > 0) vmask |= 1u << (k + 8);
  }

  __syncthreads();

  // bl output (broadcast)
#pragma unroll
  for (int c = 0; c < 3; ++c)
#pragma unroll
    for (int t = 0; t < 5; ++t)
      out[(((b * 3 + c) * 5 + t) * 512 + gy) * 512 + gx] = blv_s[c * 5 + t];

  const float w2v = w2p[0];
  f32x4 acc2[4];
#pragma unroll
  for (int u = 0; u < 4; ++u) acc2[u] = (f32x4){0.f, 0.f, 0.f, 0.f};

#pragma unroll 1
  for (int tf = 0; tf < 5; ++tf) {
    // conv2 A fragments for this frame (used after 2 barriers -> latency hidden)
    union { uint4 u; f16x8 v; } aw[5];
#pragma unroll
    for (int s = 0; s < 5; ++s)
      aw[s].u = *(const uint4*)(w2Ag + ((tf * 5 + s) * 64 + lane) * 8);

    // ---- stage x frame(s): frame f -> slot f%3 ----
    const int f_lo = (tf == 0) ? 0 : tf + 1;
    const int f_hi = (tf + 1 < 5) ? tf + 1 : 4;
    for (int f = f_lo; f <= f_hi; ++f) {
      const int slot = f % 3;
      const int fo = f * 262144;
#pragma unroll
      for (int k = 0; k < 5; ++k) {
        if (k == 4 && tid >= 176) break;
        float iv = gi[qi5[k] + fo];
        float bv = blv_s[civ5[k] + f];
        float num = iv - bv;
        float den = jv5[k] - bv + 1e-8f;
        float xv = ((vmask >> k) & 1u) ? fmaf(w2v, num * __builtin_amdgcn_rcpf(den), iv) : 0.f;
        ushort hx = f2bf(xv);
        int ebb = slot * 1320 + eb5[k];
        xsh[ebb] = hx;
        if ((vmask >> (k + 8)) & 1u) xsh[ebb + 5279] = hx;   // copy1[eb-1] = x[eb]
      }
    }
    __syncthreads();

    // ---- per-tf conv1 slot bases ----
    int baseE[8];
#pragma unroll
    for (int e = 0; e < 8; ++e) {
      int f = tf + kdE[e] - 1;
      int sl = (f < 0 || f > 4 || kdE[e] == 99) ? 3 : (f % 3);
      baseE[e] = sbase[e] + sl * 1320;
    }

    // ---- conv1 via MFMA: 21 pos-tiles over 18x18 h2 grid ----
    for (int tile = wv; tile < 21; tile += 4) {
      int pos = tile * 16 + ln;
      int pe = pos < 324 ? pos : 323;
      int y0 = pe / 18;
      int x0 = pe - y0 * 18;
      int p = x0 & 1;
      int q = y0 * 22 + x0 - p + p * 5280;
      uint u0[8], u1[8];
#pragma unroll
      for (int e = 0; e < 8; ++e) {
        const uint* pu = (const uint*)(xsh + (baseE[e] + q));
        u0[e] = pu[0]; u1[e] = pu[1];
      }
      f32x4 acc = bias4;
#pragma unroll
      for (int m = 0; m < 4; ++m) {
        union { uint4 u; bf16x8 v; } bfr;
        bfr.u = make_uint4(u0[2 * m], u1[2 * m], u0[2 * m + 1], u1[2 * m + 1]);
        acc = __builtin_amdgcn_mfma_f32_16x16x32_bf16(a4[m].v, bfr.v, acc, 0, 0, 0);
      }
      int gyh = tY * 16 - 1 + y0, gxh = tX * 16 - 1 + x0;
      bool inimg = (gyh >= 0) && (gyh < 512) && (gxh >= 0) && (gxh < 512);
      float r0 = inimg ? leakyf(acc[0]) : 0.f;
      float r1 = inimg ? leakyf(acc[1]) : 0.f;
      float r2 = inimg ? leakyf(acc[2]) : 0.f;
      float r3 = inimg ? leakyf(acc[3]) : 0.f;
      half2v p0, p1;
      p0[0] = (_Float16)r0; p0[1] = (_Float16)r1;
      p1[0] = (_Float16)r2; p1[1] = (_Float16)r3;
      if (pos < 324)
        *(uint2*)(h2sh + (y0 * 18 + x0) * 24 + kb * 4) = make_uint2(h2u(p0), h2u(p1));
    }
    __syncthreads();

    // ---- conv2 via MFMA f16: D rows = output t, accumulated across frames ----
#pragma unroll
    for (int u = 0; u < 4; ++u) {
      const int tt = wv + u * 4;
      const ushort* hb = h2sh + tt * 432;
#pragma unroll
      for (int s = 0; s < 5; ++s) {
        union { uint4 u4; f16x8 v; } bfr;
        bfr.u4 = *(const uint4*)(hb + bOff[s]);
        acc2[u] = __builtin_amdgcn_mfma_f32_16x16x32_f16(aw[s].v, bfr.v, acc2[u], 0, 0, 0);
      }
    }
    __syncthreads();
  }

  // ---- redistribute D[t][pos] through LDS (reuse xsh) and store t-output ----
  float* sredf = (float*)xsh;
#pragma unroll
  for (int u = 0; u < 4; ++u) {
    const int tt = wv + u * 4;
    if (kb == 0) {
#pragma unroll
      for (int r = 0; r < 4; ++r)
        sredf[r * 256 + tt * 16 + ln] = acc2[u][r];      // rows 0..3 = t 0..3
    } else if (kb == 1) {
      sredf[4 * 256 + tt * 16 + ln] = acc2[u][0];        // row 4 = t 4
    }
  }
  __syncthreads();

  const float bt2 = b_t2[0];
#pragma unroll
  for (int t = 0; t < 5; ++t) {
    float tv = 1.f / (1.f + __expf(-(sredf[t * 256 + tid] + bt2))) + t_bias[t];
    out[15728640 + ((b * 5 + t) * 512 + gy) * 512 + gx] = tv;
  }
}

extern "C" void kernel_launch(void* const* d_in, const int* in_sizes, int n_in,
                              void* d_out, int out_size, void* d_ws, size_t ws_size,
                              hipStream_t stream) {
  const float* gi = (const float*)d_in[0];
  const float* gj = (const float*)d_in[1];
  const float* w_bl1 = (const float*)d_in[2];
  const float* b_bl1 = (const float*)d_in[3];
  const float* w_bl2 = (const float*)d_in[4];
  const float* b_bl2 = (const float*)d_in[5];
  const float* w_t1 = (const float*)d_in[6];
  const float* b_t1 = (const float*)d_in[7];
  const float* w_t2 = (const float*)d_in[8];
  const float* b_t2 = (const float*)d_in[9];
  const float* w1 = (const float*)d_in[10];
  const float* w2 = (const float*)d_in[11];
  const float* t_bias = (const float*)d_in[12];
  float* out = (float*)d_out;
  char* ws = (char*)d_ws;

  uint* hist = (uint*)(ws + WS_HIST);
  double* sums = (double*)(ws + WS_DBL);
  float* blv = (float*)(ws + WS_BLV);
  ushort* wA = (ushort*)(ws + WS_WA);
  ushort* w2A = (ushort*)(ws + WS_W2A);

  hipMemsetAsync(ws, 0, WS_ZERO_BYTES, stream);

  setup_kernel<<<1, 256, 0, stream>>>(w_t1, w_t2, wA, w2A);
  stats_i_kernel<<<dim3(32, 60), 256, 0, stream>>>(gi, sums);
  stats_j_kernel<<<dim3(32, 12), 256, 0, stream>>>(gj, sums);
  median_hist_kernel<<<dim3(32, 4), 256, 0, stream>>>(gi, hist);
  finalize_kernel<<<1, 256, 0, stream>>>(hist, sums, w_bl1, b_bl1, w_bl2, b_bl2, w1, blv);
  fused_kernel<<<dim3(32, 32, 4), 256, 0, stream>>>(gi, gj, wA, b_t1, w2A, b_t2, w2, t_bias, blv, out);
}

// Round 6
// 206.225 us; speedup vs baseline: 5.2150x; 1.0552x over previous
//
#include <hip/hip_runtime.h>

typedef unsigned int uint;
typedef unsigned short ushort;
typedef short bf16x8 __attribute__((ext_vector_type(8)));
typedef _Float16 f16x8 __attribute__((ext_vector_type(8)));
typedef float f32x4 __attribute__((ext_vector_type(4)));

#define NEG_SLOPE 0.2f

// ---------------- workspace layout (bytes) ----------------
#define WS_HIST 0                       // 4*4096*4 = 65536
#define WS_DBL  65536                   // 88 doubles
#define WS_BLV  (WS_DBL + 704)         // 60 floats
#define WS_WA   (WS_BLV + 256)        // 16x128 bf16 = 4096 B
#define WS_W2A  (WS_WA + 4096)        // 5tf x 5step x 64lane x 8 f16 = 25600 B
#define WS_ZERO_BYTES (WS_DBL + 704)

__device__ __forceinline__ float leakyf(float x) { return fmaxf(x, NEG_SLOPE * x); }

__device__ __forceinline__ ushort f2bf(float f) {
  uint u = __float_as_uint(f);
  uint r = u + 0x7FFFu + ((u >> 16) & 1u);
  return (ushort)(r >> 16);
}
// pack 2 f32 -> 2 f16 in one dword (v_cvt_pkrtz_f16_f32)
__device__ __forceinline__ uint cvt_pk_u32(float a, float b) {
  union { __fp16 __attribute__((ext_vector_type(2))) h; uint u; } c;
  c.h = __builtin_amdgcn_cvt_pkrtz(a, b);
  return c.u;
}

// ---------------- fused stats: i-plane sums + center G/B stats + median hist + j sums ----------------
__global__ __launch_bounds__(256) void stats_kernel(const float* __restrict__ gi,
                                                    const float* __restrict__ gj,
                                                    double* __restrict__ sums,
                                                    uint* __restrict__ hist) {
  __shared__ double red[256];
  __shared__ uint lh[4096];
  const int plane = blockIdx.y;          // 0..59 = i planes, 60..71 = j planes
  const int chunk = blockIdx.x;          // 0..31
  const int tid = threadIdx.x;

  if (plane >= 60) {
    const int jp = plane - 60;           // b*3+c
    const float4* base = (const float4*)(gj + (size_t)jp * 262144);
    double dsum = 0.0;
    for (int k = 0; k < 8; ++k) {
      float4 v = base[chunk * 2048 + k * 256 + tid];
      dsum += (double)v.x + (double)v.y + (double)v.z + (double)v.w;
    }
    red[tid] = dsum; __syncthreads();
    for (int off = 128; off > 0; off >>= 1) { if (tid < off) red[tid] += red[tid + off]; __syncthreads(); }
    if (tid == 0) atomicAdd(&sums[60 + jp], red[0]);
    return;
  }

  const int b = plane / 15;
  const int rem = plane % 15;
  const int c = rem / 5;
  const int t = rem % 5;
  const float4* base = (const float4*)(gi + (size_t)plane * 262144);
  const bool dostat = (c >= 1 && t == 2);
  const bool domed = (c == 0 && t == 2);
  if (domed) {
    for (int i = tid; i < 4096; i += 256) lh[i] = 0;
    __syncthreads();
  }
  double dsum = 0.0, dsx = 0.0, dsx2 = 0.0;
  for (int k = 0; k < 8; ++k) {
    float4 v = base[chunk * 2048 + k * 256 + tid];
    dsum += (double)v.x + (double)v.y + (double)v.z + (double)v.w;
    if (dostat || domed) {
      float arr[4] = {v.x, v.y, v.z, v.w};
#pragma unroll
      for (int q = 0; q < 4; ++q) {
        float x = fminf(fmaxf(arr[q], 0.f), 1.f) * 255.f;
        if (domed) {
          int bin = (int)(x * (4096.0f / 255.0f));
          if (bin > 4095) bin = 4095;
          atomicAdd(&lh[bin], 1u);
        } else {
          dsx += (double)x;
          dsx2 += (double)x * (double)x;
        }
      }
    }
  }
  red[tid] = dsum; __syncthreads();
  for (int off = 128; off > 0; off >>= 1) { if (tid < off) red[tid] += red[tid + off]; __syncthreads(); }
  if (tid == 0) atomicAdd(&sums[plane], red[0]);
  __syncthreads();
  if (dostat) {
    red[tid] = dsx; __syncthreads();
    for (int off = 128; off > 0; off >>= 1) { if (tid < off) red[tid] += red[tid + off]; __syncthreads(); }
    if (tid == 0) atomicAdd(&sums[72 + b * 2 + (c - 1)], red[0]);
    __syncthreads();
    red[tid] = dsx2; __syncthreads();
    for (int off = 128; off > 0; off >>= 1) { if (tid < off) red[tid] += red[tid + off]; __syncthreads(); }
    if (tid == 0) atomicAdd(&sums[80 + b * 2 + (c - 1)], red[0]);
  }
  if (domed) {
    for (int i = tid; i < 4096; i += 256) { uint v = lh[i]; if (v) atomicAdd(&hist[b * 4096 + i], v); }
  }
}

// ---------------- weight prep: bf16 conv1 A (16x128) + f16 conv2 A-table ----------------
__global__ void setup_kernel(const float* __restrict__ w_t1, const float* __restrict__ w_t2,
                             ushort* __restrict__ wA, ushort* __restrict__ w2A) {
  const int tid = threadIdx.x;
  for (int idx = tid; idx < 2048; idx += 256) {
    int o = idx >> 7, k = idx & 127, g = k >> 2, kw = k & 3;
    float v = 0.f;
    if (g < 27 && kw < 3) {
      int ci = g / 9, kd = (g % 9) / 3, kh = g % 3;
      v = w_t1[o * 81 + ci * 27 + kd * 9 + kh * 3 + kw];
    }
    wA[idx] = f2bf(v);
  }
  for (int idx = tid; idx < 12800; idx += 256) {
    int j = idx & 7;
    int lane = (idx >> 3) & 63;
    int rest = idx >> 9;            // 0..24
    int step = rest % 5;
    int tf = rest / 5;
    int ln = lane & 15, kb = lane >> 4;
    int k = kb * 8 + j;
    int tap = step * 2 + (k >> 4);
    int ch = k & 15;
    float v = 0.f;
    if (ln < 5 && tap < 9) {
      int kd = tf + 1 - ln;
      if (kd >= 0 && kd <= 2) v = w_t2[ch * 27 + kd * 9 + tap];
    }
    union { ushort s; _Float16 h; } cv; cv.h = (_Float16)v;
    w2A[idx] = cv.s;
  }
}

// ---------------- finalize: median scan + stats -> MLP -> blv ----------------
__global__ __launch_bounds__(256) void finalize_kernel(const uint* __restrict__ hist,
                                const double* __restrict__ sums,
                                const float* __restrict__ w_bl1, const float* __restrict__ b_bl1,
                                const float* __restrict__ w_bl2, const float* __restrict__ b_bl2,
                                const float* __restrict__ w1, float* __restrict__ blv) {
  __shared__ uint s[256];
  __shared__ float fv[2];
  __shared__ float rmed_s[4];
  const int tid = threadIdx.x;
  for (int b = 0; b < 4; ++b) {
    const uint* h = hist + b * 4096;
    uint loc[16]; uint part = 0;
#pragma unroll
    for (int q = 0; q < 16; ++q) { loc[q] = h[tid * 16 + q]; part += loc[q]; }
    s[tid] = part; __syncthreads();
    for (int off = 1; off < 256; off <<= 1) {
      uint v = (tid >= off) ? s[tid - off] : 0u;
      __syncthreads(); s[tid] += v; __syncthreads();
    }
    uint pref = s[tid] - part;
#pragma unroll
    for (int m = 0; m < 2; ++m) {
      uint k = 131071u + (uint)m;
      if (k >= pref && k < pref + part) {
        uint cum = pref;
        for (int q = 0; q < 16; ++q) {
          if (k < cum + loc[q]) { fv[m] = ((float)(tid * 16 + q) + 0.5f) * (255.f / 4096.f); break; }
          cum += loc[q];
        }
      }
    }
    __syncthreads();
    if (tid == 0) rmed_s[b] = 0.5f * (fv[0] + fv[1]);
    __syncthreads();
  }
  if (tid < 20) {
    const int b = tid / 5, t = tid % 5;
    const double inv = 1.0 / 262144.0;
    float bl2[3];
    bl2[0] = 140.f / (1.f + 14.4f * expf(-0.034f * rmed_s[b]));
    for (int c = 1; c < 3; ++c) {
      double m = sums[72 + b * 2 + (c - 1)] * inv;
      double ex2 = sums[80 + b * 2 + (c - 1)] * inv;
      double var = ex2 - m * m;
      if (var < 0.0) var = 0.0;
      bl2[c] = (float)(1.13 * m + 1.11 * sqrt(var) - 25.6);
    }
#pragma unroll
    for (int c = 0; c < 3; ++c)
      bl2[c] = fminf(fmaxf(bl2[c], 5.f), 250.f) * (1.f / 255.f);
    float diff[3];
    for (int c = 0; c < 3; ++c)
      diff[c] = (float)((sums[(b * 3 + c) * 5 + t] - sums[60 + b * 3 + c]) * inv);
    float h1[16];
    for (int o = 0; o < 16; ++o) {
      float sv = b_bl1[o];
      for (int c = 0; c < 3; ++c) sv += w_bl1[o * 3 + c] * diff[c];
      h1[o] = leakyf(sv);
    }
    const float w1v = w1[0];
    for (int c = 0; c < 3; ++c) {
      float sv = b_bl2[c];
      for (int o = 0; o < 16; ++o) sv += w_bl2[c * 16 + o] * h1[o];
      float sg = 1.f / (1.f + expf(-sv));
      blv[(b * 3 + c) * 5 + t] = bl2[c] + w1v * sg;
    }
  }
}

// ---------------- fused: x -> conv1 (MFMA bf16) -> leaky -> conv2 (MFMA f16) -> sigmoid ----------------
// Schedule: prologue stage(0,1); per frame: conv1(tf); bar; { gi-loads(tf+2) -> conv2(tf) MFMA -> x-write(tf+2) }; bar.
__global__ __launch_bounds__(256) void fused_kernel(
    const float* __restrict__ gi, const float* __restrict__ gj,
    const ushort* __restrict__ wAg, const float* __restrict__ b_t1,
    const ushort* __restrict__ w2Ag, const float* __restrict__ b_t2,
    const float* __restrict__ w2p, const float* __restrict__ t_bias,
    const float* __restrict__ blv, float* __restrict__ out) {
  __shared__ __align__(16) ushort xsh[10560];     // 2 parity copies x 4 slots x [3][20][22] bf16
  __shared__ __align__(16) ushort h2sh[18 * 18 * 24];  // h2 f16 [18y][18x][24ch-stride]
  __shared__ float blv_s[15];

  const int b = blockIdx.z, tY = blockIdx.y, tX = blockIdx.x;
  const int tid = threadIdx.x;
  const int wv = tid >> 6;
  const int lane = tid & 63;
  const int ln = lane & 15;
  const int kb = lane >> 4;
  const int ty = tid >> 4, tx = tid & 15;
  const int gy = tY * 16 + ty, gx = tX * 16 + tx;
  const int ybase = tY * 16 - 2, xbase = tX * 16 - 2;

  if (tid < 15) blv_s[tid] = blv[b * 15 + tid];
  for (int i = tid; i < 5280; i += 256) ((uint*)xsh)[i] = 0u;

  // conv1 A fragments + bias
  union { uint4 u; bf16x8 v; } a4[4];
#pragma unroll
  for (int m = 0; m < 4; ++m)
    a4[m].u = *(const uint4*)(wAg + ln * 128 + m * 32 + kb * 8);
  f32x4 bias4;
#pragma unroll
  for (int r = 0; r < 4; ++r) bias4[r] = b_t1[kb * 4 + r];

  // conv1 per-lane k-group descriptors
  int sbase[8], kdE[8];
#pragma unroll
  for (int e = 0; e < 8; ++e) {
    int m = e >> 1, j = e & 1;
    int g = m * 8 + kb * 2 + j;
    int ci = 0, kd = 0, kh = 0;
    if (g < 27) { ci = g / 9; kd = (g % 9) / 3; kh = g % 3; } else { kd = 99; }
    sbase[e] = ci * 440 + kh * 22;
    kdE[e] = kd;
  }

  // conv1 per-tile statics (tile = wv + i*4; up to 6 tiles for wave 0)
  int qT[6], hOffT[6];
  uint tmask = 0;   // bit i: pos<324 (store valid); bit i+8: inimg
#pragma unroll
  for (int i = 0; i < 6; ++i) {
    int tile = wv + i * 4;
    int pos = tile * 16 + ln;
    int pe = pos < 324 ? pos : 323;
    int y0 = pe / 18, x0 = pe - y0 * 18;
    int p = x0 & 1;
    qT[i] = y0 * 22 + x0 - p + p * 5280;
    hOffT[i] = (y0 * 18 + x0) * 24 + kb * 4;
    int gyh = tY * 16 - 1 + y0, gxh = tX * 16 - 1 + x0;
    if (pos < 324) tmask |= 1u << i;
    if (gyh >= 0 && gyh < 512 && gxh >= 0 && gxh < 512) tmask |= 1u << (i + 8);
  }

  // conv2 per-lane B offsets (elem units)
  int bOff[5];
#pragma unroll
  for (int s = 0; s < 5; ++s) {
    int tap = s * 2 + (kb >> 1); if (tap > 8) tap = 8;
    int kh = tap / 3, kw = tap - kh * 3;
    bOff[s] = kh * 432 + kw * 24 + (kb & 1) * 8 + ln * 24;
  }

  // staging precompute (k = 0..4, idx = tid + k*256 over [3][20][20])
  int qi5[5], eb5[5], civ5[5];
  float jv5[5];
  uint vmask = 0;
#pragma unroll
  for (int k = 0; k < 5; ++k) {
    int idx = tid + k * 256;
    int idc = idx < 1200 ? idx : 0;
    int ci = idc / 400, rem = idc - ci * 400;
    int ys = rem / 20, xx = rem - ys * 20;
    int gyy = ybase + ys, gxx = xbase + xx;
    bool inb = (idx < 1200) && gyy >= 0 && gyy < 512 && gxx >= 0 && gxx < 512;
    int cy = gyy < 0 ? 0 : (gyy > 511 ? 511 : gyy);
    int cx = gxx < 0 ? 0 : (gxx > 511 ? 511 : gxx);
    int spc = cy * 512 + cx;
    qi5[k] = (b * 3 + ci) * 1310720 + spc;
    jv5[k] = gj[(b * 3 + ci) * 262144 + spc];
    eb5[k] = ci * 440 + ys * 22 + xx;
    civ5[k] = ci * 5;
    if (inb) vmask |= 1u << k;
    if (xx > 0) vmask |= 1u << (k + 8);
  }

  const float w2v = w2p[0];
  __syncthreads();   // zero-init + blv_s visible

  // ---- prologue: stage frames 0,1 (slot = f) ----
#pragma unroll
  for (int f = 0; f < 2; ++f) {
    const int fo = f * 262144;
    const int sb2 = f * 1320;
#pragma unroll
    for (int k = 0; k < 5; ++k) {
      if (k == 4 && tid >= 176) break;
      float iv = gi[qi5[k] + fo];
      float bv = blv_s[civ5[k] + f];
      float num = iv - bv;
      float den = jv5[k] - bv + 1e-8f;
      float xv = ((vmask >> k) & 1u) ? fmaf(w2v, num * __builtin_amdgcn_rcpf(den), iv) : 0.f;
      ushort hx = f2bf(xv);
      int ebb = sb2 + eb5[k];
      xsh[ebb] = hx;
      if ((vmask >> (k + 8)) & 1u) xsh[ebb + 5279] = hx;
    }
  }

  // bl output (broadcast)
#pragma unroll
  for (int c = 0; c < 3; ++c)
#pragma unroll
    for (int t = 0; t < 5; ++t)
      out[(((b * 3 + c) * 5 + t) * 512 + gy) * 512 + gx] = blv_s[c * 5 + t];

  __syncthreads();

  f32x4 acc2[4];
#pragma unroll
  for (int u = 0; u < 4; ++u) acc2[u] = (f32x4){0.f, 0.f, 0.f, 0.f};

#pragma unroll 1
  for (int tf = 0; tf < 5; ++tf) {
    // conv2 A fragments for this frame (consumed after barrier -> latency hidden)
    union { uint4 u; f16x8 v; } aw[5];
#pragma unroll
    for (int s = 0; s < 5; ++s)
      aw[s].u = *(const uint4*)(w2Ag + ((tf * 5 + s) * 64 + lane) * 8);

    // per-tf conv1 slot bases
    int baseE[8];
#pragma unroll
    for (int e = 0; e < 8; ++e) {
      int f = tf + kdE[e] - 1;
      int sl = (f < 0 || f > 4 || kdE[e] == 99) ? 3 : (f % 3);
      baseE[e] = sbase[e] + sl * 1320;
    }

    // ---- conv1 via MFMA ----
#pragma unroll
    for (int i = 0; i < 6; ++i) {
      if (i == 5 && wv != 0) continue;   // only wave 0 owns tile 20
      const int q = qT[i];
      uint u0[8], u1[8];
#pragma unroll
      for (int e = 0; e < 8; ++e) {
        const uint* pu = (const uint*)(xsh + (baseE[e] + q));
        u0[e] = pu[0]; u1[e] = pu[1];
      }
      f32x4 acc = bias4;
#pragma unroll
      for (int m = 0; m < 4; ++m) {
        union { uint4 u; bf16x8 v; } bfr;
        bfr.u = make_uint4(u0[2 * m], u1[2 * m], u0[2 * m + 1], u1[2 * m + 1]);
        acc = __builtin_amdgcn_mfma_f32_16x16x32_bf16(a4[m].v, bfr.v, acc, 0, 0, 0);
      }
      const bool inimg = (tmask >> (i + 8)) & 1u;
      float r0 = inimg ? leakyf(acc[0]) : 0.f;
      float r1 = inimg ? leakyf(acc[1]) : 0.f;
      float r2 = inimg ? leakyf(acc[2]) : 0.f;
      float r3 = inimg ? leakyf(acc[3]) : 0.f;
      uint p0 = cvt_pk_u32(r0, r1);
      uint p1 = cvt_pk_u32(r2, r3);
      if ((tmask >> i) & 1u)
        *(uint2*)(h2sh + hOffT[i]) = make_uint2(p0, p1);
    }
    __syncthreads();

    // ---- conv2(tf) MFMA  ||  stage frame tf+2 ----
    const int f2 = tf + 2;
    const bool dostage = (f2 < 5);
    float ivr[5];
    if (dostage) {
      const int fo = f2 * 262144;
      ivr[0] = gi[qi5[0] + fo];
      ivr[1] = gi[qi5[1] + fo];
      ivr[2] = gi[qi5[2] + fo];
      ivr[3] = gi[qi5[3] + fo];
      if (tid < 176) ivr[4] = gi[qi5[4] + fo];
    }

#pragma unroll
    for (int u = 0; u < 4; ++u) {
      const int tt = wv + u * 4;
      const ushort* hb = h2sh + tt * 432;
#pragma unroll
      for (int s = 0; s < 5; ++s) {
        union { uint4 u4; f16x8 v; } bfr;
        bfr.u4 = *(const uint4*)(hb + bOff[s]);
        acc2[u] = __builtin_amdgcn_mfma_f32_16x16x32_f16(aw[s].v, bfr.v, acc2[u], 0, 0, 0);
      }
    }

    if (dostage) {
      const int slot = (f2 >= 3) ? f2 - 3 : f2;   // f2 % 3
      const int sb2 = slot * 1320;
#pragma unroll
      for (int k = 0; k < 5; ++k) {
        if (k == 4 && tid >= 176) break;
        float iv = ivr[k];
        float bv = blv_s[civ5[k] + f2];
        float num = iv - bv;
        float den = jv5[k] - bv + 1e-8f;
        float xv = ((vmask >> k) & 1u) ? fmaf(w2v, num * __builtin_amdgcn_rcpf(den), iv) : 0.f;
        ushort hx = f2bf(xv);
        int ebb = sb2 + eb5[k];
        xsh[ebb] = hx;
        if ((vmask >> (k + 8)) & 1u) xsh[ebb + 5279] = hx;
      }
    }
    __syncthreads();
  }

  // ---- redistribute D[t][pos] through LDS (reuse xsh) and store t-output ----
  float* sredf = (float*)xsh;
#pragma unroll
  for (int u = 0; u < 4; ++u) {
    const int tt = wv + u * 4;
    if (kb == 0) {
#pragma unroll
      for (int r = 0; r < 4; ++r)
        sredf[r * 256 + tt * 16 + ln] = acc2[u][r];      // rows 0..3 = t 0..3
    } else if (kb == 1) {
      sredf[4 * 256 + tt * 16 + ln] = acc2[u][0];        // row 4 = t 4
    }
  }
  __syncthreads();

  const float bt2 = b_t2[0];
#pragma unroll
  for (int t = 0; t < 5; ++t) {
    float tv = 1.f / (1.f + __expf(-(sredf[t * 256 + tid] + bt2))) + t_bias[t];
    out[15728640 + ((b * 5 + t) * 512 + gy) * 512 + gx] = tv;
  }
}

extern "C" void kernel_launch(void* const* d_in, const int* in_sizes, int n_in,
                              void* d_out, int out_size, void* d_ws, size_t ws_size,
                              hipStream_t stream) {
  const float* gi = (const float*)d_in[0];
  const float* gj = (const float*)d_in[1];
  const float* w_bl1 = (const float*)d_in[2];
  const float* b_bl1 = (const float*)d_in[3];
  const float* w_bl2 = (const float*)d_in[4];
  const float* b_bl2 = (const float*)d_in[5];
  const float* w_t1 = (const float*)d_in[6];
  const float* b_t1 = (const float*)d_in[7];
  const float* w_t2 = (const float*)d_in[8];
  const float* b_t2 = (const float*)d_in[9];
  const float* w1 = (const float*)d_in[10];
  const float* w2 = (const float*)d_in[11];
  const float* t_bias = (const float*)d_in[12];
  float* out = (float*)d_out;
  char* ws = (char*)d_ws;

  uint* hist = (uint*)(ws + WS_HIST);
  double* sums = (double*)(ws + WS_DBL);
  float* blv = (float*)(ws + WS_BLV);
  ushort* wA = (ushort*)(ws + WS_WA);
  ushort* w2A = (ushort*)(ws + WS_W2A);

  hipMemsetAsync(ws, 0, WS_ZERO_BYTES, stream);

  setup_kernel<<<1, 256, 0, stream>>>(w_t1, w_t2, wA, w2A);
  stats_kernel<<<dim3(32, 72), 256, 0, stream>>>(gi, gj, sums, hist);
  finalize_kernel<<<1, 256, 0, stream>>>(hist, sums, w_bl1, b_bl1, w_bl2, b_bl2, w1, blv);
  fused_kernel<<<dim3(32, 32, 4), 256, 0, stream>>>(gi, gj, wA, b_t1, w2A, b_t2, w2, t_bias, blv, out);
}